// Round 10
// baseline (313.103 us; speedup 1.0000x reference)
//
#include <hip/hip_runtime.h>
#include <hip/hip_bf16.h>

#define NEGV (-10000.0f)
constexpr int B_ = 32, S_ = 256, D_ = 512, K_ = 8, L_ = 64;

typedef __bf16 bf16_t;
typedef bf16_t bf16x8 __attribute__((ext_vector_type(8)));
typedef float f32x4 __attribute__((ext_vector_type(4)));

__device__ __forceinline__ float u2f(unsigned int u) {
  union { unsigned int u; float f; } x; x.u = u; return x.f;
}
__device__ __forceinline__ unsigned int f2bfbits(float f) {
  union { bf16_t h; unsigned short u; } x; x.h = (bf16_t)f; return (unsigned int)x.u;
}
// DPP row rotate-right by 1: dst[l] = src[(l&48) | ((l-1)&15)]  (verified by
// v8's absmax=0.0).
__device__ __forceinline__ float row_ror1(float x) {
  union { float f; int i; } a, r;
  a.f = x;
  r.i = __builtin_amdgcn_update_dpp(a.i, a.i, 0x121, 0xF, 0xF, false);
  return r.f;
}

// ---------------------------------------------------------------------------
// cast word_rep -> bf16 Awr [8192][512]; blocks >= 2048 cast cls_w -> bf16.
// ---------------------------------------------------------------------------
__global__ __launch_bounds__(256) void cast_kernel(const float* __restrict__ wr,
                                                   bf16_t* __restrict__ Awr,
                                                   const float* __restrict__ cls_w,
                                                   bf16_t* __restrict__ clsb) {
  const int bid = blockIdx.x;
  if (bid < 2048) {
    const int i = (bid * 256 + threadIdx.x) * 8;
    const float4 a = *(const float4*)(wr + i);
    const float4 b = *(const float4*)(wr + i + 4);
    bf16x8 o;
    o[0] = (bf16_t)a.x; o[1] = (bf16_t)a.y; o[2] = (bf16_t)a.z; o[3] = (bf16_t)a.w;
    o[4] = (bf16_t)b.x; o[5] = (bf16_t)b.y; o[6] = (bf16_t)b.z; o[7] = (bf16_t)b.w;
    *(bf16x8*)(Awr + i) = o;
  } else {
    const int i = ((bid - 2048) * 256 + threadIdx.x) * 8;
    const float4 a = *(const float4*)(cls_w + i);
    const float4 b = *(const float4*)(cls_w + i + 4);
    bf16x8 o;
    o[0] = (bf16_t)a.x; o[1] = (bf16_t)a.y; o[2] = (bf16_t)a.z; o[3] = (bf16_t)a.w;
    o[4] = (bf16_t)b.x; o[5] = (bf16_t)b.y; o[6] = (bf16_t)b.z; o[7] = (bf16_t)b.w;
    *(bf16x8*)(clsb + i) = o;
  }
}

// ---------------------------------------------------------------------------
// w2 (unchanged): per k one MFMA GEMM, A direct from global.
// ---------------------------------------------------------------------------
__global__ __launch_bounds__(256) void w2_kernel(const float* __restrict__ conv_w,
                                                 const bf16_t* __restrict__ clsb,
                                                 bf16_t* __restrict__ Vt) {
  const int k = blockIdx.y;
  const int m0 = blockIdx.x * 128;
  const int tid = threadIdx.x;
  const int w = tid >> 6, lane = tid & 63;
  const int wm = w & 1, wn = w >> 1;
  const int lrow = lane & 15, quad = lane >> 4;
  const float* A = conv_w + (size_t)k * 2097152;
  f32x4 acc[4][2] = {};
#pragma unroll 2
  for (int kk = 0; kk < 16; kk++) {
    const int d0 = kk * 32 + quad * 8;
    const bf16x8 b0 = *(const bf16x8*)(clsb + (wn * 32 + lrow) * 512 + kk * 32 + quad * 8);
    const bf16x8 b1 = *(const bf16x8*)(clsb + (wn * 32 + 16 + lrow) * 512 + kk * 32 + quad * 8);
#pragma unroll
    for (int mi = 0; mi < 4; mi++) {
      const int ih = m0 + wm * 64 + mi * 16 + lrow;
      const float* ap = A + (size_t)d0 * 4096 + ih;
      bf16x8 a;
      a[0] = (bf16_t)ap[0 * 4096]; a[1] = (bf16_t)ap[1 * 4096];
      a[2] = (bf16_t)ap[2 * 4096]; a[3] = (bf16_t)ap[3 * 4096];
      a[4] = (bf16_t)ap[4 * 4096]; a[5] = (bf16_t)ap[5 * 4096];
      a[6] = (bf16_t)ap[6 * 4096]; a[7] = (bf16_t)ap[7 * 4096];
      acc[mi][0] = __builtin_amdgcn_mfma_f32_16x16x32_bf16(a, b0, acc[mi][0], 0, 0, 0);
      acc[mi][1] = __builtin_amdgcn_mfma_f32_16x16x32_bf16(a, b1, acc[mi][1], 0, 0, 0);
    }
  }
#pragma unroll
  for (int mi = 0; mi < 4; mi++) {
#pragma unroll
    for (int dd = 0; dd < 4; dd++) {
      const int ih = m0 + wm * 64 + mi * 16 + quad * 4 + dd;
      const int i = ih >> 3, h = ih & 7;
      const int o = k - h;
      if (o >= 0) {
#pragma unroll
        for (int ni = 0; ni < 2; ni++) {
          const int l = wn * 32 + ni * 16 + lrow;
          Vt[(size_t)(k * 64 + l) * 4096 + o * 512 + i] = (bf16_t)acc[mi][ni][dd];
        }
      }
    }
  }
}

// ---------------------------------------------------------------------------
// bias2 (unchanged)
// ---------------------------------------------------------------------------
__global__ __launch_bounds__(256) void bias2_kernel(const float* __restrict__ conv_b,
                                                    const float* __restrict__ cls_w,
                                                    const float* __restrict__ cls_b,
                                                    float* __restrict__ bias2) {
  const int k = blockIdx.x;
  const int tid = threadIdx.x;
  const int l = tid & 63, c = tid >> 6;
  __shared__ float partb[4][64];
  float s = 0.f;
  for (int d = c * 128; d < c * 128 + 128; d++)
    s += conv_b[k * D_ + d] * cls_w[l * D_ + d];
  partb[c][l] = s;
  __syncthreads();
  if (tid < 64)
    bias2[k * 64 + tid] = cls_b[tid] + partb[0][tid] + partb[1][tid] + partb[2][tid] + partb[3][tid];
}

// ---------------------------------------------------------------------------
// ls v4 (unchanged): A-window resident in LDS, one wave per strip,
// barrier-free K-loop, cross-wave packed-dword epilogue. grid (128, 2).
// ---------------------------------------------------------------------------
__global__ __launch_bounds__(256) void ls_mfma(const bf16_t* __restrict__ Awr,
                                               const bf16_t* __restrict__ Vt,
                                               const float* __restrict__ bias2,
                                               const int* __restrict__ mask,
                                               unsigned int* __restrict__ ELSd) {
  constexpr int LDA = 520;
  __shared__ __align__(16) bf16_t As[71 * LDA];  // 73.8 KB
  const int tid = threadIdx.x;
  const int m0 = blockIdx.x * 64;
  const int y = blockIdx.y;
  const int w = tid >> 6, lane = tid & 63;
  const int lrow = lane & 15, quad = lane >> 4;
  const int tblA[4] = {7, 0, 5, 2}, tblB[4] = {6, 1, 4, 3};
  const int kS = (y == 0) ? tblA[w] : tblB[w];

  // stage A rows m0-7 .. m0+63 (71 rows x 512) once
  for (int c = tid; c < 71 * 64; c += 256) {
    const int row = c >> 6, col8 = c & 63;
    int src = m0 - 7 + row;
    if (src < 0) src = 0;
    const uint4 v = *(const uint4*)(Awr + (size_t)src * 512 + col8 * 8);
    *(uint4*)(&As[row * LDA + col8 * 8]) = v;
  }
  __syncthreads();

  f32x4 acc[4][4] = {};  // [mi][ni] : 64m x 64l
  const int NJ = 16 * (kS + 1);
  const bf16_t* vbase = Vt + (size_t)(kS * 64 + lrow) * 4096 + quad * 8;
#pragma unroll 2
  for (int j = 0; j < NJ; j++) {
    const int o = j >> 4;
    const int col = (j & 15) * 32;
    bf16x8 bfr[4];
#pragma unroll
    for (int ni = 0; ni < 4; ni++)
      bfr[ni] = *(const bf16x8*)(vbase + (size_t)(ni * 16) * 4096 + j * 32);
    const int abase = (lrow + 7 - o) * LDA + col + quad * 8;
#pragma unroll
    for (int mi = 0; mi < 4; mi++) {
      const bf16x8 a = *(const bf16x8*)(&As[abase + mi * 16 * LDA]);
#pragma unroll
      for (int ni = 0; ni < 4; ni++)
        acc[mi][ni] = __builtin_amdgcn_mfma_f32_16x16x32_bf16(a, bfr[ni], acc[mi][ni], 0, 0, 0);
    }
  }

  // epilogue: bias + exp + bf16, park in LDS, then packed-dword coalesced store
  __syncthreads();  // all A reads done; reuse As as buf[4][64][64] u16 (32 KB)
  unsigned short* buf = (unsigned short*)As;
#pragma unroll
  for (int ni = 0; ni < 4; ni++) {
    const int l = ni * 16 + lrow;
    const float bn = bias2[kS * 64 + l];
#pragma unroll
    for (int mi = 0; mi < 4; mi++) {
#pragma unroll
      for (int d = 0; d < 4; d++) {
        const int ml = mi * 16 + quad * 4 + d;
        const int m = m0 + ml;
        const int t = m & 255;
        const bool mok = (mask[m] == 1) && (t >= kS) && (l != 0);
        const float e = mok ? __expf(acc[mi][ni][d] + bn) : 0.f;
        buf[w * 4096 + ml * 64 + l] = (unsigned short)f2bfbits(e);
      }
    }
  }
  __syncthreads();
  // planes: (w0,w1) -> plane y (lo=k(7-y) from w0, hi=k(y) from w1);
  //         (w2,w3) -> plane 2+y.
#pragma unroll
  for (int g = 0; g < 2; g++) {
    const int plane = g * 2 + y;
    const unsigned short* lo = buf + (g * 2) * 4096;
    const unsigned short* hi = buf + (g * 2 + 1) * 4096;
#pragma unroll
    for (int it = 0; it < 16; it++) {
      const int idx = it * 256 + tid;
      const unsigned int dw = (unsigned int)lo[idx] | ((unsigned int)hi[idx] << 16);
      ELSd[((size_t)plane * 8192 + m0 + (idx >> 6)) * 64 + (idx & 63)] = dw;
    }
  }
}

// ---------------------------------------------------------------------------
// dp v9: v8's verified systolic structure with the exp(T) table held in 16
// NAMED f32x4 variables (no array anywhere -> nothing for SROA to demote;
// rule-#20-proof) and the u-loop expanded via macro so every register
// reference is fully static. Indexing identical to v8 (absmax 0.0):
//   table(q, i) = exp(T[l][ (((l&48)|((l-i)&15)) + 16q) & 63 ])
//   phase bases e[(l+16q)&63] via __shfl; row_ror1 advances i.
// Falsifiable signature: VGPR_Count must jump ~68 -> ~120+.
// ---------------------------------------------------------------------------
__global__ __launch_bounds__(64, 1) void dp_kernel(const float* __restrict__ T,
                                                   const float* __restrict__ Tfb_g,
                                                   const unsigned int* __restrict__ ELSd,
                                                   float* __restrict__ Mg_lin,
                                                   float* __restrict__ cs_g) {
  const int b = blockIdx.x;
  const int l = threadIdx.x;  // 0..63

  const float* Trow = T + l * 64;
#define TE(Q, I) __expf(Trow[((((l & 48) | ((l - (I)) & 15)) + 16 * (Q)) & 63)])
#define MKT(VAR, Q, C) \
  const f32x4 VAR = { TE(Q, (C)*4 + 0), TE(Q, (C)*4 + 1), TE(Q, (C)*4 + 2), TE(Q, (C)*4 + 3) };
  MKT(tA0, 0, 0) MKT(tA1, 0, 1) MKT(tA2, 0, 2) MKT(tA3, 0, 3)
  MKT(tB0, 1, 0) MKT(tB1, 1, 1) MKT(tB2, 1, 2) MKT(tB3, 1, 3)
  MKT(tC0, 2, 0) MKT(tC1, 2, 1) MKT(tC2, 2, 2) MKT(tC3, 2, 3)
  MKT(tD0, 3, 0) MKT(tD1, 3, 1) MKT(tD2, 3, 2) MKT(tD3, 3, 3)
#undef MKT
#undef TE

  const unsigned int* e0p = ELSd + ((size_t)0 * 8192 + b * 256) * 64 + l;
  const unsigned int* e1p = ELSd + ((size_t)1 * 8192 + b * 256) * 64 + l;
  const unsigned int* e2p = ELSd + ((size_t)2 * 8192 + b * 256) * 64 + l;
  const unsigned int* e3p = ELSd + ((size_t)3 * 8192 + b * 256) * 64 + l;

  float mh0 = __expf(Tfb_g[l]);
  float mh1 = 0.f, mh2 = 0.f, mh3 = 0.f, mh4 = 0.f, mh5 = 0.f, mh6 = 0.f, mh7 = 0.f;
  float c = 0.f;
  float m4 = 0.f;
  float S_next = 0.f;

  const int lq1 = (l + 16) & 63, lq2 = (l + 32) & 63, lq3 = (l + 48) & 63;

  uint4 r0 = make_uint4(e0p[0 * 64], e1p[0 * 64], e2p[0 * 64], e3p[0 * 64]);
  uint4 r1 = make_uint4(e0p[1 * 64], e1p[1 * 64], e2p[1 * 64], e3p[1 * 64]);
  uint4 r2 = make_uint4(e0p[2 * 64], e1p[2 * 64], e2p[2 * 64], e3p[2 * 64]);
  uint4 r3 = make_uint4(e0p[3 * 64], e1p[3 * 64], e2p[3 * 64], e3p[3 * 64]);

#define RND(TA, TB, TC, TD, E) \
  a0 += TA[E] * v0; a1 += TB[E] * v1; a2 += TC[E] * v2; a3 += TD[E] * v3;
#define RNDS(TA, TB, TC, TD, E)                         \
  a0 += TA[E] * v0; s0 += v0; a1 += TB[E] * v1; s1 += v1; \
  a2 += TC[E] * v2; s2 += v2; a3 += TD[E] * v3; s3 += v3;
#define ROT \
  v0 = row_ror1(v0); v1 = row_ror1(v1); v2 = row_ror1(v2); v3 = row_ror1(v3);

#define DP_STEP(U, RQ)                                                          \
  {                                                                             \
    const int t = t4 + (U);                                                     \
    if ((U) == 0) {                                                             \
      if (t4 > 0) {                                                             \
        const float S = fmaxf(S_next, 1e-30f);                                  \
        const float inv = __builtin_amdgcn_rcpf(S);                             \
        c += __logf(S);                                                         \
        mh7 = mh6 * inv; mh6 = mh5 * inv; mh5 = mh4 * inv; mh4 = mh3 * inv;     \
        mh3 = mh2 * inv; mh2 = mh1 * inv; mh1 = mh0 * inv; mh0 = m4 * inv;      \
      }                                                                         \
    } else {                                                                    \
      mh7 = mh6; mh6 = mh5; mh5 = mh4; mh4 = mh3;                               \
      mh3 = mh2; mh2 = mh1; mh1 = mh0; mh0 = m4;                                \
    }                                                                           \
    const float f7 = u2f(RQ.x << 16), fk0 = u2f(RQ.x & 0xFFFF0000u);            \
    const float f6 = u2f(RQ.y << 16), fk1 = u2f(RQ.y & 0xFFFF0000u);            \
    const float f5 = u2f(RQ.z << 16), fk2 = u2f(RQ.z & 0xFFFF0000u);            \
    const float f4 = u2f(RQ.w << 16), fk3 = u2f(RQ.w & 0xFFFF0000u);            \
    const float e = ((fk0 * mh0 + fk1 * mh1) + (fk2 * mh2 + fk3 * mh3)) +       \
                    ((f4 * mh4 + f5 * mh5) + (f6 * mh6 + f7 * mh7));            \
    const float eb1 = __shfl(e, lq1);                                           \
    const float eb2 = __shfl(e, lq2);                                           \
    const float eb3 = __shfl(e, lq3);                                           \
    {                                                                           \
      int nt = t + 4; if (nt > 255) nt = 255;                                   \
      RQ = make_uint4(e0p[(size_t)nt * 64], e1p[(size_t)nt * 64],               \
                      e2p[(size_t)nt * 64], e3p[(size_t)nt * 64]);              \
    }                                                                           \
    float a0 = 0.f, a1 = 0.f, a2 = 0.f, a3 = 0.f;                               \
    float v0 = e, v1 = eb1, v2 = eb2, v3 = eb3;                                 \
    if ((U) == 3) {                                                             \
      float s0 = 0.f, s1 = 0.f, s2 = 0.f, s3 = 0.f;                             \
      RNDS(tA0, tB0, tC0, tD0, 0) ROT RNDS(tA0, tB0, tC0, tD0, 1) ROT           \
      RNDS(tA0, tB0, tC0, tD0, 2) ROT RNDS(tA0, tB0, tC0, tD0, 3) ROT           \
      RNDS(tA1, tB1, tC1, tD1, 0) ROT RNDS(tA1, tB1, tC1, tD1, 1) ROT           \
      RNDS(tA1, tB1, tC1, tD1, 2) ROT RNDS(tA1, tB1, tC1, tD1, 3) ROT           \
      RNDS(tA2, tB2, tC2, tD2, 0) ROT RNDS(tA2, tB2, tC2, tD2, 1) ROT           \
      RNDS(tA2, tB2, tC2, tD2, 2) ROT RNDS(tA2, tB2, tC2, tD2, 3) ROT           \
      RNDS(tA3, tB3, tC3, tD3, 0) ROT RNDS(tA3, tB3, tC3, tD3, 1) ROT           \
      RNDS(tA3, tB3, tC3, tD3, 2) ROT RNDS(tA3, tB3, tC3, tD3, 3)               \
      S_next = (s0 + s1) + (s2 + s3);                                           \
    } else {                                                                    \
      RND(tA0, tB0, tC0, tD0, 0) ROT RND(tA0, tB0, tC0, tD0, 1) ROT             \
      RND(tA0, tB0, tC0, tD0, 2) ROT RND(tA0, tB0, tC0, tD0, 3) ROT             \
      RND(tA1, tB1, tC1, tD1, 0) ROT RND(tA1, tB1, tC1, tD1, 1) ROT             \
      RND(tA1, tB1, tC1, tD1, 2) ROT RND(tA1, tB1, tC1, tD1, 3) ROT             \
      RND(tA2, tB2, tC2, tD2, 0) ROT RND(tA2, tB2, tC2, tD2, 1) ROT             \
      RND(tA2, tB2, tC2, tD2, 2) ROT RND(tA2, tB2, tC2, tD2, 3) ROT             \
      RND(tA3, tB3, tC3, tD3, 0) ROT RND(tA3, tB3, tC3, tD3, 1) ROT             \
      RND(tA3, tB3, tC3, tD3, 2) ROT RND(tA3, tB3, tC3, tD3, 3)                 \
    }                                                                           \
    m4 = (a0 + a1) + (a2 + a3);                                                 \
    Mg_lin[((size_t)b * 256 + t) * 64 + l] = m4;                                \
    if (l == 0) cs_g[b * 256 + t] = c;                                          \
  }

  for (int t4 = 0; t4 < 256; t4 += 4) {
    DP_STEP(0, r0)
    DP_STEP(1, r1)
    DP_STEP(2, r2)
    DP_STEP(3, r3)
  }
#undef DP_STEP
#undef RND
#undef RNDS
#undef ROT
}

// ---------------------------------------------------------------------------
// Final gather (unchanged)
// ---------------------------------------------------------------------------
__global__ __launch_bounds__(64) void final_kernel(const int* __restrict__ mask,
                                                   const float* __restrict__ Tfb_g,
                                                   const float* __restrict__ T2e_g,
                                                   const unsigned int* __restrict__ ELSd,
                                                   const float* __restrict__ Mg_lin,
                                                   const float* __restrict__ cs_g,
                                                   float* __restrict__ out) {
  const int b = blockIdx.x, lane = threadIdx.x;
  int lenp = 0;
  for (int s = lane; s < S_; s += 64) lenp += (mask[b * S_ + s] == 1) ? 1 : 0;
#pragma unroll
  for (int off = 32; off > 0; off >>= 1) lenp += __shfl_xor(lenp, off);
  const int len = lenp;
  const float t2e = T2e_g[lane];
  float vals[8];
  float mx = -3.4e38f;
#pragma unroll
  for (int k = 0; k < 8; k++) {
    int tk = len - 1 - k;
    if (tk < 0) tk = S_ - 1;
    float g;
    if (k > tk) {
      g = NEGV;
    } else {
      const int p = (k < 4) ? k : (7 - k);
      const unsigned int dw = ELSd[((size_t)p * 8192 + b * 256 + tk) * 64 + lane];
      const float elsv = (k < 4) ? u2f(dw & 0xFFFF0000u) : u2f(dw << 16);
      const float ls = (elsv > 0.f) ? __logf(elsv) : NEGV;
      if (k == tk) {
        g = ls + Tfb_g[lane];
      } else if (mask[b * S_ + tk] == 1) {
        const int u = tk - 1 - k;
        const float mlin = Mg_lin[((size_t)b * S_ + u) * 64 + lane];
        const float M = (mlin > 0.f) ? (__logf(mlin) + cs_g[b * S_ + u]) : -1e30f;
        g = ls + M;
      } else {
        g = NEGV;
      }
    }
    const float v = g + t2e;
    vals[k] = v;
    mx = fmaxf(mx, v);
  }
#pragma unroll
  for (int off = 32; off > 0; off >>= 1) mx = fmaxf(mx, __shfl_xor(mx, off));
  float s = 0.f;
#pragma unroll
  for (int k = 0; k < 8; k++) s += __expf(vals[k] - mx);
#pragma unroll
  for (int off = 32; off > 0; off >>= 1) s += __shfl_xor(s, off);
  if (lane == 0) out[b] = __logf(s) + mx;
}

// ---------------------------------------------------------------------------
extern "C" void kernel_launch(void* const* d_in, const int* in_sizes, int n_in,
                              void* d_out, int out_size, void* d_ws, size_t ws_size,
                              hipStream_t stream) {
  const float* wr     = (const float*)d_in[0];
  const int*   mask   = (const int*)d_in[1];
  const float* conv_w = (const float*)d_in[2];
  const float* conv_b = (const float*)d_in[3];
  const float* cls_w  = (const float*)d_in[4];
  const float* cls_b  = (const float*)d_in[5];
  const float* T      = (const float*)d_in[6];
  const float* Tfb    = (const float*)d_in[7];
  const float* T2e    = (const float*)d_in[8];
  float* out = (float*)d_out;

  float* ws = (float*)d_ws;
  bf16_t* Vt    = (bf16_t*)ws;                      // [512][4096] bf16 (4 MB)
  bf16_t* Awr   = (bf16_t*)(ws + 1048576);          // [8192][512] bf16 (8 MB)
  float*  bias2 = ws + 3145728;                     // [8][64]
  unsigned int* ELSd = (unsigned int*)(ws + 3146240);  // [4][8192][64] dwords (8 MB)
  float*  Mg    = ws + 5243392;                     // [32][256][64] (2 MB)
  float*  cs    = ws + 5767680;                     // [32][256]
  bf16_t* clsb  = (bf16_t*)(ws + 5775872);          // [64][512] bf16

  cast_kernel<<<2064, 256, 0, stream>>>(wr, Awr, cls_w, clsb);
  w2_kernel<<<dim3(32, 8), 256, 0, stream>>>(conv_w, clsb, Vt);
  bias2_kernel<<<8, 256, 0, stream>>>(conv_b, cls_w, cls_b, bias2);
  ls_mfma<<<dim3(128, 2), 256, 0, stream>>>(Awr, Vt, bias2, mask, ELSd);
  dp_kernel<<<32, 64, 0, stream>>>(T, Tfb, ELSd, Mg, cs);
  final_kernel<<<32, 64, 0, stream>>>(mask, Tfb, T2e, ELSd, Mg, cs, out);
}

// Round 11
// 313.018 us; speedup vs baseline: 1.0003x; 1.0003x over previous
//
#include <hip/hip_runtime.h>
#include <hip/hip_bf16.h>

#define NEGV (-10000.0f)
constexpr int B_ = 32, S_ = 256, D_ = 512, K_ = 8, L_ = 64;

typedef __bf16 bf16_t;
typedef bf16_t bf16x8 __attribute__((ext_vector_type(8)));
typedef float f32x4 __attribute__((ext_vector_type(4)));

__device__ __forceinline__ float u2f(unsigned int u) {
  union { unsigned int u; float f; } x; x.u = u; return x.f;
}
__device__ __forceinline__ unsigned int f2bfbits(float f) {
  union { bf16_t h; unsigned short u; } x; x.h = (bf16_t)f; return (unsigned int)x.u;
}
// DPP row rotate-right by 1: dst[l] = src[(l&48) | ((l-1)&15)]  (verified by
// v8/v9 absmax=0.0).
__device__ __forceinline__ float row_ror1(float x) {
  union { float f; int i; } a, r;
  a.f = x;
  r.i = __builtin_amdgcn_update_dpp(a.i, a.i, 0x121, 0xF, 0xF, false);
  return r.f;
}

// ---------------------------------------------------------------------------
// cast word_rep -> bf16 Awr [8192][512]; blocks >= 2048 cast cls_w -> bf16.
// ---------------------------------------------------------------------------
__global__ __launch_bounds__(256) void cast_kernel(const float* __restrict__ wr,
                                                   bf16_t* __restrict__ Awr,
                                                   const float* __restrict__ cls_w,
                                                   bf16_t* __restrict__ clsb) {
  const int bid = blockIdx.x;
  if (bid < 2048) {
    const int i = (bid * 256 + threadIdx.x) * 8;
    const float4 a = *(const float4*)(wr + i);
    const float4 b = *(const float4*)(wr + i + 4);
    bf16x8 o;
    o[0] = (bf16_t)a.x; o[1] = (bf16_t)a.y; o[2] = (bf16_t)a.z; o[3] = (bf16_t)a.w;
    o[4] = (bf16_t)b.x; o[5] = (bf16_t)b.y; o[6] = (bf16_t)b.z; o[7] = (bf16_t)b.w;
    *(bf16x8*)(Awr + i) = o;
  } else {
    const int i = ((bid - 2048) * 256 + threadIdx.x) * 8;
    const float4 a = *(const float4*)(cls_w + i);
    const float4 b = *(const float4*)(cls_w + i + 4);
    bf16x8 o;
    o[0] = (bf16_t)a.x; o[1] = (bf16_t)a.y; o[2] = (bf16_t)a.z; o[3] = (bf16_t)a.w;
    o[4] = (bf16_t)b.x; o[5] = (bf16_t)b.y; o[6] = (bf16_t)b.z; o[7] = (bf16_t)b.w;
    *(bf16x8*)(clsb + i) = o;
  }
}

// ---------------------------------------------------------------------------
// w2 (unchanged): per k one MFMA GEMM, A direct from global.
// ---------------------------------------------------------------------------
__global__ __launch_bounds__(256) void w2_kernel(const float* __restrict__ conv_w,
                                                 const bf16_t* __restrict__ clsb,
                                                 bf16_t* __restrict__ Vt) {
  const int k = blockIdx.y;
  const int m0 = blockIdx.x * 128;
  const int tid = threadIdx.x;
  const int w = tid >> 6, lane = tid & 63;
  const int wm = w & 1, wn = w >> 1;
  const int lrow = lane & 15, quad = lane >> 4;
  const float* A = conv_w + (size_t)k * 2097152;
  f32x4 acc[4][2] = {};
#pragma unroll 2
  for (int kk = 0; kk < 16; kk++) {
    const int d0 = kk * 32 + quad * 8;
    const bf16x8 b0 = *(const bf16x8*)(clsb + (wn * 32 + lrow) * 512 + kk * 32 + quad * 8);
    const bf16x8 b1 = *(const bf16x8*)(clsb + (wn * 32 + 16 + lrow) * 512 + kk * 32 + quad * 8);
#pragma unroll
    for (int mi = 0; mi < 4; mi++) {
      const int ih = m0 + wm * 64 + mi * 16 + lrow;
      const float* ap = A + (size_t)d0 * 4096 + ih;
      bf16x8 a;
      a[0] = (bf16_t)ap[0 * 4096]; a[1] = (bf16_t)ap[1 * 4096];
      a[2] = (bf16_t)ap[2 * 4096]; a[3] = (bf16_t)ap[3 * 4096];
      a[4] = (bf16_t)ap[4 * 4096]; a[5] = (bf16_t)ap[5 * 4096];
      a[6] = (bf16_t)ap[6 * 4096]; a[7] = (bf16_t)ap[7 * 4096];
      acc[mi][0] = __builtin_amdgcn_mfma_f32_16x16x32_bf16(a, b0, acc[mi][0], 0, 0, 0);
      acc[mi][1] = __builtin_amdgcn_mfma_f32_16x16x32_bf16(a, b1, acc[mi][1], 0, 0, 0);
    }
  }
#pragma unroll
  for (int mi = 0; mi < 4; mi++) {
#pragma unroll
    for (int dd = 0; dd < 4; dd++) {
      const int ih = m0 + wm * 64 + mi * 16 + quad * 4 + dd;
      const int i = ih >> 3, h = ih & 7;
      const int o = k - h;
      if (o >= 0) {
#pragma unroll
        for (int ni = 0; ni < 2; ni++) {
          const int l = wn * 32 + ni * 16 + lrow;
          Vt[(size_t)(k * 64 + l) * 4096 + o * 512 + i] = (bf16_t)acc[mi][ni][dd];
        }
      }
    }
  }
}

// ---------------------------------------------------------------------------
// bias2 (unchanged)
// ---------------------------------------------------------------------------
__global__ __launch_bounds__(256) void bias2_kernel(const float* __restrict__ conv_b,
                                                    const float* __restrict__ cls_w,
                                                    const float* __restrict__ cls_b,
                                                    float* __restrict__ bias2) {
  const int k = blockIdx.x;
  const int tid = threadIdx.x;
  const int l = tid & 63, c = tid >> 6;
  __shared__ float partb[4][64];
  float s = 0.f;
  for (int d = c * 128; d < c * 128 + 128; d++)
    s += conv_b[k * D_ + d] * cls_w[l * D_ + d];
  partb[c][l] = s;
  __syncthreads();
  if (tid < 64)
    bias2[k * 64 + tid] = cls_b[tid] + partb[0][tid] + partb[1][tid] + partb[2][tid] + partb[3][tid];
}

// ---------------------------------------------------------------------------
// ls v4 (unchanged): A-window resident in LDS, one wave per strip,
// barrier-free K-loop, cross-wave packed-dword epilogue. grid (128, 2).
// ---------------------------------------------------------------------------
__global__ __launch_bounds__(256) void ls_mfma(const bf16_t* __restrict__ Awr,
                                               const bf16_t* __restrict__ Vt,
                                               const float* __restrict__ bias2,
                                               const int* __restrict__ mask,
                                               unsigned int* __restrict__ ELSd) {
  constexpr int LDA = 520;
  __shared__ __align__(16) bf16_t As[71 * LDA];  // 73.8 KB
  const int tid = threadIdx.x;
  const int m0 = blockIdx.x * 64;
  const int y = blockIdx.y;
  const int w = tid >> 6, lane = tid & 63;
  const int lrow = lane & 15, quad = lane >> 4;
  const int tblA[4] = {7, 0, 5, 2}, tblB[4] = {6, 1, 4, 3};
  const int kS = (y == 0) ? tblA[w] : tblB[w];

  // stage A rows m0-7 .. m0+63 (71 rows x 512) once
  for (int c = tid; c < 71 * 64; c += 256) {
    const int row = c >> 6, col8 = c & 63;
    int src = m0 - 7 + row;
    if (src < 0) src = 0;
    const uint4 v = *(const uint4*)(Awr + (size_t)src * 512 + col8 * 8);
    *(uint4*)(&As[row * LDA + col8 * 8]) = v;
  }
  __syncthreads();

  f32x4 acc[4][4] = {};  // [mi][ni] : 64m x 64l
  const int NJ = 16 * (kS + 1);
  const bf16_t* vbase = Vt + (size_t)(kS * 64 + lrow) * 4096 + quad * 8;
#pragma unroll 2
  for (int j = 0; j < NJ; j++) {
    const int o = j >> 4;
    const int col = (j & 15) * 32;
    bf16x8 bfr[4];
#pragma unroll
    for (int ni = 0; ni < 4; ni++)
      bfr[ni] = *(const bf16x8*)(vbase + (size_t)(ni * 16) * 4096 + j * 32);
    const int abase = (lrow + 7 - o) * LDA + col + quad * 8;
#pragma unroll
    for (int mi = 0; mi < 4; mi++) {
      const bf16x8 a = *(const bf16x8*)(&As[abase + mi * 16 * LDA]);
#pragma unroll
      for (int ni = 0; ni < 4; ni++)
        acc[mi][ni] = __builtin_amdgcn_mfma_f32_16x16x32_bf16(a, bfr[ni], acc[mi][ni], 0, 0, 0);
    }
  }

  // epilogue: bias + exp + bf16, park in LDS, then packed-dword coalesced store
  __syncthreads();  // all A reads done; reuse As as buf[4][64][64] u16 (32 KB)
  unsigned short* buf = (unsigned short*)As;
#pragma unroll
  for (int ni = 0; ni < 4; ni++) {
    const int l = ni * 16 + lrow;
    const float bn = bias2[kS * 64 + l];
#pragma unroll
    for (int mi = 0; mi < 4; mi++) {
#pragma unroll
      for (int d = 0; d < 4; d++) {
        const int ml = mi * 16 + quad * 4 + d;
        const int m = m0 + ml;
        const int t = m & 255;
        const bool mok = (mask[m] == 1) && (t >= kS) && (l != 0);
        const float e = mok ? __expf(acc[mi][ni][d] + bn) : 0.f;
        buf[w * 4096 + ml * 64 + l] = (unsigned short)f2bfbits(e);
      }
    }
  }
  __syncthreads();
  // planes: (w0,w1) -> plane y (lo=k(7-y) from w0, hi=k(y) from w1);
  //         (w2,w3) -> plane 2+y.
#pragma unroll
  for (int g = 0; g < 2; g++) {
    const int plane = g * 2 + y;
    const unsigned short* lo = buf + (g * 2) * 4096;
    const unsigned short* hi = buf + (g * 2 + 1) * 4096;
#pragma unroll
    for (int it = 0; it < 16; it++) {
      const int idx = it * 256 + tid;
      const unsigned int dw = (unsigned int)lo[idx] | ((unsigned int)hi[idx] << 16);
      ELSd[((size_t)plane * 8192 + m0 + (idx >> 6)) * 64 + (idx & 63)] = dw;
    }
  }
}

// ---------------------------------------------------------------------------
// dp v10: v9's verified systolic arithmetic + the two knobs that bind the
// register allocator:
//  (1) amdgpu_waves_per_eu(1,1): occupancy TARGET = 1 wave/EU (launch_bounds'
//      2nd arg only sets the minimum guarantee; the pre-RA scheduler still
//      targeted max occupancy and rematerialized the exp(T) table into the
//      loop -> VGPR stuck at 68, ~340 VALU instrs/step).
//  (2) asm "+v" opacity on all 16 table vectors: values cannot be
//      rematerialized at all; with budget 512 VGPRs the only sane choice is
//      keeping them live.
// Falsifiable signature: VGPR_Count must jump 68 -> >=100.
// ---------------------------------------------------------------------------
__global__ __launch_bounds__(64)
__attribute__((amdgpu_waves_per_eu(1, 1)))
void dp_kernel(const float* __restrict__ T,
               const float* __restrict__ Tfb_g,
               const unsigned int* __restrict__ ELSd,
               float* __restrict__ Mg_lin,
               float* __restrict__ cs_g) {
  const int b = blockIdx.x;
  const int l = threadIdx.x;  // 0..63

  const float* Trow = T + l * 64;
#define TE(Q, I) __expf(Trow[((((l & 48) | ((l - (I)) & 15)) + 16 * (Q)) & 63)])
#define MKT(VAR, Q, C) \
  f32x4 VAR = { TE(Q, (C)*4 + 0), TE(Q, (C)*4 + 1), TE(Q, (C)*4 + 2), TE(Q, (C)*4 + 3) };
  MKT(tA0, 0, 0) MKT(tA1, 0, 1) MKT(tA2, 0, 2) MKT(tA3, 0, 3)
  MKT(tB0, 1, 0) MKT(tB1, 1, 1) MKT(tB2, 1, 2) MKT(tB3, 1, 3)
  MKT(tC0, 2, 0) MKT(tC1, 2, 1) MKT(tC2, 2, 2) MKT(tC3, 2, 3)
  MKT(tD0, 3, 0) MKT(tD1, 3, 1) MKT(tD2, 3, 2) MKT(tD3, 3, 3)
#undef MKT
#undef TE
  // opacity: no rematerialization possible
  asm volatile("" : "+v"(tA0), "+v"(tA1), "+v"(tA2), "+v"(tA3));
  asm volatile("" : "+v"(tB0), "+v"(tB1), "+v"(tB2), "+v"(tB3));
  asm volatile("" : "+v"(tC0), "+v"(tC1), "+v"(tC2), "+v"(tC3));
  asm volatile("" : "+v"(tD0), "+v"(tD1), "+v"(tD2), "+v"(tD3));

  const unsigned int* e0p = ELSd + ((size_t)0 * 8192 + b * 256) * 64 + l;
  const unsigned int* e1p = ELSd + ((size_t)1 * 8192 + b * 256) * 64 + l;
  const unsigned int* e2p = ELSd + ((size_t)2 * 8192 + b * 256) * 64 + l;
  const unsigned int* e3p = ELSd + ((size_t)3 * 8192 + b * 256) * 64 + l;

  float mh0 = __expf(Tfb_g[l]);
  float mh1 = 0.f, mh2 = 0.f, mh3 = 0.f, mh4 = 0.f, mh5 = 0.f, mh6 = 0.f, mh7 = 0.f;
  float c = 0.f;
  float m4 = 0.f;
  float S_next = 0.f;

  const int lq1 = (l + 16) & 63, lq2 = (l + 32) & 63, lq3 = (l + 48) & 63;

  uint4 r0 = make_uint4(e0p[0 * 64], e1p[0 * 64], e2p[0 * 64], e3p[0 * 64]);
  uint4 r1 = make_uint4(e0p[1 * 64], e1p[1 * 64], e2p[1 * 64], e3p[1 * 64]);
  uint4 r2 = make_uint4(e0p[2 * 64], e1p[2 * 64], e2p[2 * 64], e3p[2 * 64]);
  uint4 r3 = make_uint4(e0p[3 * 64], e1p[3 * 64], e2p[3 * 64], e3p[3 * 64]);

#define RND(TA, TB, TC, TD, E) \
  a0 += TA[E] * v0; a1 += TB[E] * v1; a2 += TC[E] * v2; a3 += TD[E] * v3;
#define RNDS(TA, TB, TC, TD, E)                         \
  a0 += TA[E] * v0; s0 += v0; a1 += TB[E] * v1; s1 += v1; \
  a2 += TC[E] * v2; s2 += v2; a3 += TD[E] * v3; s3 += v3;
#define ROT \
  v0 = row_ror1(v0); v1 = row_ror1(v1); v2 = row_ror1(v2); v3 = row_ror1(v3);

#define DP_STEP(U, RQ)                                                          \
  {                                                                             \
    const int t = t4 + (U);                                                     \
    if ((U) == 0) {                                                             \
      if (t4 > 0) {                                                             \
        const float S = fmaxf(S_next, 1e-30f);                                  \
        const float inv = __builtin_amdgcn_rcpf(S);                             \
        c += __logf(S);                                                         \
        mh7 = mh6 * inv; mh6 = mh5 * inv; mh5 = mh4 * inv; mh4 = mh3 * inv;     \
        mh3 = mh2 * inv; mh2 = mh1 * inv; mh1 = mh0 * inv; mh0 = m4 * inv;      \
      }                                                                         \
    } else {                                                                    \
      mh7 = mh6; mh6 = mh5; mh5 = mh4; mh4 = mh3;                               \
      mh3 = mh2; mh2 = mh1; mh1 = mh0; mh0 = m4;                                \
    }                                                                           \
    const float f7 = u2f(RQ.x << 16), fk0 = u2f(RQ.x & 0xFFFF0000u);            \
    const float f6 = u2f(RQ.y << 16), fk1 = u2f(RQ.y & 0xFFFF0000u);            \
    const float f5 = u2f(RQ.z << 16), fk2 = u2f(RQ.z & 0xFFFF0000u);            \
    const float f4 = u2f(RQ.w << 16), fk3 = u2f(RQ.w & 0xFFFF0000u);            \
    const float e = ((fk0 * mh0 + fk1 * mh1) + (fk2 * mh2 + fk3 * mh3)) +       \
                    ((f4 * mh4 + f5 * mh5) + (f6 * mh6 + f7 * mh7));            \
    const float eb1 = __shfl(e, lq1);                                           \
    const float eb2 = __shfl(e, lq2);                                           \
    const float eb3 = __shfl(e, lq3);                                           \
    {                                                                           \
      int nt = t + 4; if (nt > 255) nt = 255;                                   \
      RQ = make_uint4(e0p[(size_t)nt * 64], e1p[(size_t)nt * 64],               \
                      e2p[(size_t)nt * 64], e3p[(size_t)nt * 64]);              \
    }                                                                           \
    float a0 = 0.f, a1 = 0.f, a2 = 0.f, a3 = 0.f;                               \
    float v0 = e, v1 = eb1, v2 = eb2, v3 = eb3;                                 \
    if ((U) == 3) {                                                             \
      float s0 = 0.f, s1 = 0.f, s2 = 0.f, s3 = 0.f;                             \
      RNDS(tA0, tB0, tC0, tD0, 0) ROT RNDS(tA0, tB0, tC0, tD0, 1) ROT           \
      RNDS(tA0, tB0, tC0, tD0, 2) ROT RNDS(tA0, tB0, tC0, tD0, 3) ROT           \
      RNDS(tA1, tB1, tC1, tD1, 0) ROT RNDS(tA1, tB1, tC1, tD1, 1) ROT           \
      RNDS(tA1, tB1, tC1, tD1, 2) ROT RNDS(tA1, tB1, tC1, tD1, 3) ROT           \
      RNDS(tA2, tB2, tC2, tD2, 0) ROT RNDS(tA2, tB2, tC2, tD2, 1) ROT           \
      RNDS(tA2, tB2, tC2, tD2, 2) ROT RNDS(tA2, tB2, tC2, tD2, 3) ROT           \
      RNDS(tA3, tB3, tC3, tD3, 0) ROT RNDS(tA3, tB3, tC3, tD3, 1) ROT           \
      RNDS(tA3, tB3, tC3, tD3, 2) ROT RNDS(tA3, tB3, tC3, tD3, 3)               \
      S_next = (s0 + s1) + (s2 + s3);                                           \
    } else {                                                                    \
      RND(tA0, tB0, tC0, tD0, 0) ROT RND(tA0, tB0, tC0, tD0, 1) ROT             \
      RND(tA0, tB0, tC0, tD0, 2) ROT RND(tA0, tB0, tC0, tD0, 3) ROT             \
      RND(tA1, tB1, tC1, tD1, 0) ROT RND(tA1, tB1, tC1, tD1, 1) ROT             \
      RND(tA1, tB1, tC1, tD1, 2) ROT RND(tA1, tB1, tC1, tD1, 3) ROT             \
      RND(tA2, tB2, tC2, tD2, 0) ROT RND(tA2, tB2, tC2, tD2, 1) ROT             \
      RND(tA2, tB2, tC2, tD2, 2) ROT RND(tA2, tB2, tC2, tD2, 3) ROT             \
      RND(tA3, tB3, tC3, tD3, 0) ROT RND(tA3, tB3, tC3, tD3, 1) ROT             \
      RND(tA3, tB3, tC3, tD3, 2) ROT RND(tA3, tB3, tC3, tD3, 3)                 \
    }                                                                           \
    m4 = (a0 + a1) + (a2 + a3);                                                 \
    Mg_lin[((size_t)b * 256 + t) * 64 + l] = m4;                                \
    if (l == 0) cs_g[b * 256 + t] = c;                                          \
  }

  for (int t4 = 0; t4 < 256; t4 += 4) {
    DP_STEP(0, r0)
    DP_STEP(1, r1)
    DP_STEP(2, r2)
    DP_STEP(3, r3)
  }
#undef DP_STEP
#undef RND
#undef RNDS
#undef ROT
}

// ---------------------------------------------------------------------------
// Final gather (unchanged)
// ---------------------------------------------------------------------------
__global__ __launch_bounds__(64) void final_kernel(const int* __restrict__ mask,
                                                   const float* __restrict__ Tfb_g,
                                                   const float* __restrict__ T2e_g,
                                                   const unsigned int* __restrict__ ELSd,
                                                   const float* __restrict__ Mg_lin,
                                                   const float* __restrict__ cs_g,
                                                   float* __restrict__ out) {
  const int b = blockIdx.x, lane = threadIdx.x;
  int lenp = 0;
  for (int s = lane; s < S_; s += 64) lenp += (mask[b * S_ + s] == 1) ? 1 : 0;
#pragma unroll
  for (int off = 32; off > 0; off >>= 1) lenp += __shfl_xor(lenp, off);
  const int len = lenp;
  const float t2e = T2e_g[lane];
  float vals[8];
  float mx = -3.4e38f;
#pragma unroll
  for (int k = 0; k < 8; k++) {
    int tk = len - 1 - k;
    if (tk < 0) tk = S_ - 1;
    float g;
    if (k > tk) {
      g = NEGV;
    } else {
      const int p = (k < 4) ? k : (7 - k);
      const unsigned int dw = ELSd[((size_t)p * 8192 + b * 256 + tk) * 64 + lane];
      const float elsv = (k < 4) ? u2f(dw & 0xFFFF0000u) : u2f(dw << 16);
      const float ls = (elsv > 0.f) ? __logf(elsv) : NEGV;
      if (k == tk) {
        g = ls + Tfb_g[lane];
      } else if (mask[b * S_ + tk] == 1) {
        const int u = tk - 1 - k;
        const float mlin = Mg_lin[((size_t)b * S_ + u) * 64 + lane];
        const float M = (mlin > 0.f) ? (__logf(mlin) + cs_g[b * S_ + u]) : -1e30f;
        g = ls + M;
      } else {
        g = NEGV;
      }
    }
    const float v = g + t2e;
    vals[k] = v;
    mx = fmaxf(mx, v);
  }
#pragma unroll
  for (int off = 32; off > 0; off >>= 1) mx = fmaxf(mx, __shfl_xor(mx, off));
  float s = 0.f;
#pragma unroll
  for (int k = 0; k < 8; k++) s += __expf(vals[k] - mx);
#pragma unroll
  for (int off = 32; off > 0; off >>= 1) s += __shfl_xor(s, off);
  if (lane == 0) out[b] = __logf(s) + mx;
}

// ---------------------------------------------------------------------------
extern "C" void kernel_launch(void* const* d_in, const int* in_sizes, int n_in,
                              void* d_out, int out_size, void* d_ws, size_t ws_size,
                              hipStream_t stream) {
  const float* wr     = (const float*)d_in[0];
  const int*   mask   = (const int*)d_in[1];
  const float* conv_w = (const float*)d_in[2];
  const float* conv_b = (const float*)d_in[3];
  const float* cls_w  = (const float*)d_in[4];
  const float* cls_b  = (const float*)d_in[5];
  const float* T      = (const float*)d_in[6];
  const float* Tfb    = (const float*)d_in[7];
  const float* T2e    = (const float*)d_in[8];
  float* out = (float*)d_out;

  float* ws = (float*)d_ws;
  bf16_t* Vt    = (bf16_t*)ws;                      // [512][4096] bf16 (4 MB)
  bf16_t* Awr   = (bf16_t*)(ws + 1048576);          // [8192][512] bf16 (8 MB)
  float*  bias2 = ws + 3145728;                     // [8][64]
  unsigned int* ELSd = (unsigned int*)(ws + 3146240);  // [4][8192][64] dwords (8 MB)
  float*  Mg    = ws + 5243392;                     // [32][256][64] (2 MB)
  float*  cs    = ws + 5767680;                     // [32][256]
  bf16_t* clsb  = (bf16_t*)(ws + 5775872);          // [64][512] bf16

  cast_kernel<<<2064, 256, 0, stream>>>(wr, Awr, cls_w, clsb);
  w2_kernel<<<dim3(32, 8), 256, 0, stream>>>(conv_w, clsb, Vt);
  bias2_kernel<<<8, 256, 0, stream>>>(conv_b, cls_w, cls_b, bias2);
  ls_mfma<<<dim3(128, 2), 256, 0, stream>>>(Awr, Vt, bias2, mask, ELSd);
  dp_kernel<<<32, 64, 0, stream>>>(T, Tfb, ELSd, Mg, cs);
  final_kernel<<<32, 64, 0, stream>>>(mask, Tfb, T2e, ELSd, Mg, cs, out);
}

// Round 12
// 287.994 us; speedup vs baseline: 1.0872x; 1.0869x over previous
//
#include <hip/hip_runtime.h>
#include <hip/hip_bf16.h>

#define NEGV (-10000.0f)
constexpr int B_ = 32, S_ = 256, D_ = 512, K_ = 8, L_ = 64;

typedef __bf16 bf16_t;
typedef bf16_t bf16x8 __attribute__((ext_vector_type(8)));
typedef float f32x4 __attribute__((ext_vector_type(4)));

__device__ __forceinline__ float u2f(unsigned int u) {
  union { unsigned int u; float f; } x; x.u = u; return x.f;
}
__device__ __forceinline__ unsigned int f2bfbits(float f) {
  union { bf16_t h; unsigned short u; } x; x.h = (bf16_t)f; return (unsigned int)x.u;
}

// ---------------------------------------------------------------------------
// cast word_rep -> bf16 Awr [8192][512]; blocks >= 2048 cast cls_w -> bf16.
// ---------------------------------------------------------------------------
__global__ __launch_bounds__(256) void cast_kernel(const float* __restrict__ wr,
                                                   bf16_t* __restrict__ Awr,
                                                   const float* __restrict__ cls_w,
                                                   bf16_t* __restrict__ clsb) {
  const int bid = blockIdx.x;
  if (bid < 2048) {
    const int i = (bid * 256 + threadIdx.x) * 8;
    const float4 a = *(const float4*)(wr + i);
    const float4 b = *(const float4*)(wr + i + 4);
    bf16x8 o;
    o[0] = (bf16_t)a.x; o[1] = (bf16_t)a.y; o[2] = (bf16_t)a.z; o[3] = (bf16_t)a.w;
    o[4] = (bf16_t)b.x; o[5] = (bf16_t)b.y; o[6] = (bf16_t)b.z; o[7] = (bf16_t)b.w;
    *(bf16x8*)(Awr + i) = o;
  } else {
    const int i = ((bid - 2048) * 256 + threadIdx.x) * 8;
    const float4 a = *(const float4*)(cls_w + i);
    const float4 b = *(const float4*)(cls_w + i + 4);
    bf16x8 o;
    o[0] = (bf16_t)a.x; o[1] = (bf16_t)a.y; o[2] = (bf16_t)a.z; o[3] = (bf16_t)a.w;
    o[4] = (bf16_t)b.x; o[5] = (bf16_t)b.y; o[6] = (bf16_t)b.z; o[7] = (bf16_t)b.w;
    *(bf16x8*)(clsb + i) = o;
  }
}

// ---------------------------------------------------------------------------
// w2 v2: per k one MFMA GEMM (unchanged) + bias2 absorbed into blockIdx.x==0
// (saves the separate bias2 launch; ls runs only after w2 completes, so the
// bias2 values are ready).
// ---------------------------------------------------------------------------
__global__ __launch_bounds__(256) void w2_kernel(const float* __restrict__ conv_w,
                                                 const bf16_t* __restrict__ clsb,
                                                 bf16_t* __restrict__ Vt,
                                                 const float* __restrict__ conv_b,
                                                 const float* __restrict__ cls_w,
                                                 const float* __restrict__ cls_b,
                                                 float* __restrict__ bias2) {
  const int k = blockIdx.y;
  const int m0 = blockIdx.x * 128;
  const int tid = threadIdx.x;
  const int w = tid >> 6, lane = tid & 63;
  const int wm = w & 1, wn = w >> 1;
  const int lrow = lane & 15, quad = lane >> 4;
  const float* A = conv_w + (size_t)k * 2097152;
  f32x4 acc[4][2] = {};
#pragma unroll 2
  for (int kk = 0; kk < 16; kk++) {
    const int d0 = kk * 32 + quad * 8;
    const bf16x8 b0 = *(const bf16x8*)(clsb + (wn * 32 + lrow) * 512 + kk * 32 + quad * 8);
    const bf16x8 b1 = *(const bf16x8*)(clsb + (wn * 32 + 16 + lrow) * 512 + kk * 32 + quad * 8);
#pragma unroll
    for (int mi = 0; mi < 4; mi++) {
      const int ih = m0 + wm * 64 + mi * 16 + lrow;
      const float* ap = A + (size_t)d0 * 4096 + ih;
      bf16x8 a;
      a[0] = (bf16_t)ap[0 * 4096]; a[1] = (bf16_t)ap[1 * 4096];
      a[2] = (bf16_t)ap[2 * 4096]; a[3] = (bf16_t)ap[3 * 4096];
      a[4] = (bf16_t)ap[4 * 4096]; a[5] = (bf16_t)ap[5 * 4096];
      a[6] = (bf16_t)ap[6 * 4096]; a[7] = (bf16_t)ap[7 * 4096];
      acc[mi][0] = __builtin_amdgcn_mfma_f32_16x16x32_bf16(a, b0, acc[mi][0], 0, 0, 0);
      acc[mi][1] = __builtin_amdgcn_mfma_f32_16x16x32_bf16(a, b1, acc[mi][1], 0, 0, 0);
    }
  }
#pragma unroll
  for (int mi = 0; mi < 4; mi++) {
#pragma unroll
    for (int dd = 0; dd < 4; dd++) {
      const int ih = m0 + wm * 64 + mi * 16 + quad * 4 + dd;
      const int i = ih >> 3, h = ih & 7;
      const int o = k - h;
      if (o >= 0) {
#pragma unroll
        for (int ni = 0; ni < 2; ni++) {
          const int l = wn * 32 + ni * 16 + lrow;
          Vt[(size_t)(k * 64 + l) * 4096 + o * 512 + i] = (bf16_t)acc[mi][ni][dd];
        }
      }
    }
  }
  // absorbed bias2 (one block per k)
  if (blockIdx.x == 0) {
    __shared__ float partb[4][64];
    const int bl = tid & 63, bc = tid >> 6;
    float s = 0.f;
    for (int d = bc * 128; d < bc * 128 + 128; d++)
      s += conv_b[k * D_ + d] * cls_w[bl * D_ + d];
    partb[bc][bl] = s;
    __syncthreads();
    if (tid < 64)
      bias2[k * 64 + tid] = cls_b[tid] + partb[0][tid] + partb[1][tid] + partb[2][tid] + partb[3][tid];
  }
}

// ---------------------------------------------------------------------------
// ls v4 (unchanged): A-window resident in LDS, one wave per strip,
// barrier-free K-loop, cross-wave packed-dword epilogue. grid (128, 2).
// ---------------------------------------------------------------------------
__global__ __launch_bounds__(256) void ls_mfma(const bf16_t* __restrict__ Awr,
                                               const bf16_t* __restrict__ Vt,
                                               const float* __restrict__ bias2,
                                               const int* __restrict__ mask,
                                               unsigned int* __restrict__ ELSd) {
  constexpr int LDA = 520;
  __shared__ __align__(16) bf16_t As[71 * LDA];  // 73.8 KB
  const int tid = threadIdx.x;
  const int m0 = blockIdx.x * 64;
  const int y = blockIdx.y;
  const int w = tid >> 6, lane = tid & 63;
  const int lrow = lane & 15, quad = lane >> 4;
  const int tblA[4] = {7, 0, 5, 2}, tblB[4] = {6, 1, 4, 3};
  const int kS = (y == 0) ? tblA[w] : tblB[w];

  for (int c = tid; c < 71 * 64; c += 256) {
    const int row = c >> 6, col8 = c & 63;
    int src = m0 - 7 + row;
    if (src < 0) src = 0;
    const uint4 v = *(const uint4*)(Awr + (size_t)src * 512 + col8 * 8);
    *(uint4*)(&As[row * LDA + col8 * 8]) = v;
  }
  __syncthreads();

  f32x4 acc[4][4] = {};  // [mi][ni] : 64m x 64l
  const int NJ = 16 * (kS + 1);
  const bf16_t* vbase = Vt + (size_t)(kS * 64 + lrow) * 4096 + quad * 8;
#pragma unroll 2
  for (int j = 0; j < NJ; j++) {
    const int o = j >> 4;
    const int col = (j & 15) * 32;
    bf16x8 bfr[4];
#pragma unroll
    for (int ni = 0; ni < 4; ni++)
      bfr[ni] = *(const bf16x8*)(vbase + (size_t)(ni * 16) * 4096 + j * 32);
    const int abase = (lrow + 7 - o) * LDA + col + quad * 8;
#pragma unroll
    for (int mi = 0; mi < 4; mi++) {
      const bf16x8 a = *(const bf16x8*)(&As[abase + mi * 16 * LDA]);
#pragma unroll
      for (int ni = 0; ni < 4; ni++)
        acc[mi][ni] = __builtin_amdgcn_mfma_f32_16x16x32_bf16(a, bfr[ni], acc[mi][ni], 0, 0, 0);
    }
  }

  __syncthreads();  // reuse As as buf[4][64][64] u16
  unsigned short* buf = (unsigned short*)As;
#pragma unroll
  for (int ni = 0; ni < 4; ni++) {
    const int l = ni * 16 + lrow;
    const float bn = bias2[kS * 64 + l];
#pragma unroll
    for (int mi = 0; mi < 4; mi++) {
#pragma unroll
      for (int d = 0; d < 4; d++) {
        const int ml = mi * 16 + quad * 4 + d;
        const int m = m0 + ml;
        const int t = m & 255;
        const bool mok = (mask[m] == 1) && (t >= kS) && (l != 0);
        const float e = mok ? __expf(acc[mi][ni][d] + bn) : 0.f;
        buf[w * 4096 + ml * 64 + l] = (unsigned short)f2bfbits(e);
      }
    }
  }
  __syncthreads();
#pragma unroll
  for (int g = 0; g < 2; g++) {
    const int plane = g * 2 + y;
    const unsigned short* lo = buf + (g * 2) * 4096;
    const unsigned short* hi = buf + (g * 2 + 1) * 4096;
#pragma unroll
    for (int it = 0; it < 16; it++) {
      const int idx = it * 256 + tid;
      const unsigned int dw = (unsigned int)lo[idx] | ((unsigned int)hi[idx] << 16);
      ELSd[((size_t)plane * 8192 + m0 + (idx >> 6)) * 64 + (idx & 63)] = dw;
    }
  }
}

// ---------------------------------------------------------------------------
// dp v11: v6 (verified 91.2 us) + software-pipelined decode. The recurrence
// is linear: e_{t+1} = P0(t+1)*m4_t + pe_t with
//   pe_t = P1*mh0 + P2*mh1 + ... + P7*mh6   (step-t state, t+1 planes)
// so pe and the full plane decode are computed INSIDE the LDS write->read
// stall window of step t. Critical path per step collapses to
//   m4 -> 1 FMA -> ds_write -> 16 broadcast ds_read_b128 -> 4-chain dot -> m4.
// Rescale (every 4th step) folds in exactly: e = inv*(P0*m4 + pe), mh *= inv,
// c += log S with S = sum_j e (wave-uniform, v6-verified). 4-way split
// accumulators shorten the dot tail. Same table idiom as v6 (f32x4 rTv[16],
// proven register-resident at VGPR=88).
// ---------------------------------------------------------------------------
__global__ __launch_bounds__(64) void dp_kernel(const float* __restrict__ T,
                                                const float* __restrict__ Tfb_g,
                                                const unsigned int* __restrict__ ELSd,
                                                float* __restrict__ Mg_lin,
                                                float* __restrict__ cs_g) {
  const int b = blockIdx.x;
  const int l = threadIdx.x;  // 0..63
  __shared__ __align__(16) float ebuf[64];

  f32x4 rTv[16];
#pragma unroll
  for (int jj = 0; jj < 16; jj++) {
    const float4 tv = *(const float4*)(T + l * 64 + jj * 4);
    rTv[jj][0] = __expf(tv.x);
    rTv[jj][1] = __expf(tv.y);
    rTv[jj][2] = __expf(tv.z);
    rTv[jj][3] = __expf(tv.w);
  }

  const unsigned int* e0p = ELSd + ((size_t)0 * 8192 + b * 256) * 64 + l;
  const unsigned int* e1p = ELSd + ((size_t)1 * 8192 + b * 256) * 64 + l;
  const unsigned int* e2p = ELSd + ((size_t)2 * 8192 + b * 256) * 64 + l;
  const unsigned int* e3p = ELSd + ((size_t)3 * 8192 + b * 256) * 64 + l;

  float mh0 = __expf(Tfb_g[l]);
  float mh1 = 0.f, mh2 = 0.f, mh3 = 0.f, mh4 = 0.f, mh5 = 0.f, mh6 = 0.f, mh7 = 0.f;
  float c = 0.f;
  float m4 = 0.f;
  float S_next = 0.f;

  uint4 r0 = make_uint4(e0p[0 * 64], e1p[0 * 64], e2p[0 * 64], e3p[0 * 64]);
  uint4 r1 = make_uint4(e0p[1 * 64], e1p[1 * 64], e2p[1 * 64], e3p[1 * 64]);
  uint4 r2 = make_uint4(e0p[2 * 64], e1p[2 * 64], e2p[2 * 64], e3p[2 * 64]);
  uint4 r3 = make_uint4(e0p[3 * 64], e1p[3 * 64], e2p[3 * 64], e3p[3 * 64]);

  // e for t=0: only mh0 nonzero -> e0 = P0(0)*mh0
  float e = u2f(r0.x & 0xFFFF0000u) * mh0;

  // STEP(U, RQ, RN): RQ holds planes(t) (refilled to t+4 here);
  //                  RN holds planes(t+1) (decoded here for pe / next e).
#define DP_STEP(U, RQ, RN)                                                      \
  {                                                                             \
    const int t = t4 + (U);                                                     \
    ebuf[l] = e;                                                                \
    /* decode NEXT step's planes (fills the LDS stall window) */                \
    const float nf7 = u2f(RN.x << 16), nk0 = u2f(RN.x & 0xFFFF0000u);           \
    const float nf6 = u2f(RN.y << 16), nk1 = u2f(RN.y & 0xFFFF0000u);           \
    const float nf5 = u2f(RN.z << 16), nk2 = u2f(RN.z & 0xFFFF0000u);           \
    const float nf4 = u2f(RN.w << 16), nk3 = u2f(RN.w & 0xFFFF0000u);           \
    const float pe = ((nk1 * mh0 + nk2 * mh1) + (nk3 * mh2 + nf4 * mh3)) +      \
                     ((nf5 * mh4 + nf6 * mh5) + nf7 * mh6);                     \
    /* refill RQ <- planes(t+4) */                                              \
    {                                                                           \
      int nt = t + 4; if (nt > 255) nt = 255;                                   \
      RQ = make_uint4(e0p[(size_t)nt * 64], e1p[(size_t)nt * 64],               \
                      e2p[(size_t)nt * 64], e3p[(size_t)nt * 64]);              \
    }                                                                           \
    /* dot: 4 independent accumulator chains */                                 \
    const f32x4* ev = (const f32x4*)ebuf;                                       \
    f32x4 A0 = {0.f, 0.f, 0.f, 0.f}, A1 = {0.f, 0.f, 0.f, 0.f};                 \
    f32x4 A2 = {0.f, 0.f, 0.f, 0.f}, A3 = {0.f, 0.f, 0.f, 0.f};                 \
    if ((U) == 3) {                                                             \
      f32x4 s0 = {0.f, 0.f, 0.f, 0.f}, s1 = {0.f, 0.f, 0.f, 0.f};               \
      _Pragma("unroll")                                                         \
      for (int jj = 0; jj < 4; jj++) {                                          \
        const f32x4 v0 = ev[jj], v1 = ev[4 + jj], v2 = ev[8 + jj], v3 = ev[12 + jj]; \
        A0 += rTv[jj] * v0; A1 += rTv[4 + jj] * v1;                             \
        A2 += rTv[8 + jj] * v2; A3 += rTv[12 + jj] * v3;                        \
        s0 += v0 + v2; s1 += v1 + v3;                                           \
      }                                                                         \
      const f32x4 ss = s0 + s1;                                                 \
      S_next = (ss[0] + ss[1]) + (ss[2] + ss[3]);                               \
    } else {                                                                    \
      _Pragma("unroll")                                                         \
      for (int jj = 0; jj < 4; jj++) {                                          \
        A0 += rTv[jj] * ev[jj]; A1 += rTv[4 + jj] * ev[4 + jj];                 \
        A2 += rTv[8 + jj] * ev[8 + jj]; A3 += rTv[12 + jj] * ev[12 + jj];       \
      }                                                                         \
    }                                                                           \
    const f32x4 As4 = (A0 + A1) + (A2 + A3);                                    \
    m4 = (As4[0] + As4[1]) + (As4[2] + As4[3]);                                 \
    Mg_lin[((size_t)b * 256 + t) * 64 + l] = m4;                                \
    if (l == 0) cs_g[b * 256 + t] = c;                                          \
    /* advance to t+1: shift history, form next e (1-2 ops on critical path) */ \
    if ((U) == 3) {                                                             \
      const float S = fmaxf(S_next, 1e-30f);                                    \
      const float inv = __builtin_amdgcn_rcpf(S);                               \
      c += __logf(S);                                                           \
      mh7 = mh6 * inv; mh6 = mh5 * inv; mh5 = mh4 * inv; mh4 = mh3 * inv;       \
      mh3 = mh2 * inv; mh2 = mh1 * inv; mh1 = mh0 * inv; mh0 = m4 * inv;        \
      e = inv * (nk0 * m4 + pe);                                                \
    } else {                                                                    \
      mh7 = mh6; mh6 = mh5; mh5 = mh4; mh4 = mh3;                               \
      mh3 = mh2; mh2 = mh1; mh1 = mh0; mh0 = m4;                                \
      e = nk0 * m4 + pe;                                                        \
    }                                                                           \
  }

  for (int t4 = 0; t4 < 256; t4 += 4) {
    DP_STEP(0, r0, r1)
    DP_STEP(1, r1, r2)
    DP_STEP(2, r2, r3)
    DP_STEP(3, r3, r0)
  }
#undef DP_STEP
}

// ---------------------------------------------------------------------------
// Final gather (unchanged)
// ---------------------------------------------------------------------------
__global__ __launch_bounds__(64) void final_kernel(const int* __restrict__ mask,
                                                   const float* __restrict__ Tfb_g,
                                                   const float* __restrict__ T2e_g,
                                                   const unsigned int* __restrict__ ELSd,
                                                   const float* __restrict__ Mg_lin,
                                                   const float* __restrict__ cs_g,
                                                   float* __restrict__ out) {
  const int b = blockIdx.x, lane = threadIdx.x;
  int lenp = 0;
  for (int s = lane; s < S_; s += 64) lenp += (mask[b * S_ + s] == 1) ? 1 : 0;
#pragma unroll
  for (int off = 32; off > 0; off >>= 1) lenp += __shfl_xor(lenp, off);
  const int len = lenp;
  const float t2e = T2e_g[lane];
  float vals[8];
  float mx = -3.4e38f;
#pragma unroll
  for (int k = 0; k < 8; k++) {
    int tk = len - 1 - k;
    if (tk < 0) tk = S_ - 1;
    float g;
    if (k > tk) {
      g = NEGV;
    } else {
      const int p = (k < 4) ? k : (7 - k);
      const unsigned int dw = ELSd[((size_t)p * 8192 + b * 256 + tk) * 64 + lane];
      const float elsv = (k < 4) ? u2f(dw & 0xFFFF0000u) : u2f(dw << 16);
      const float ls = (elsv > 0.f) ? __logf(elsv) : NEGV;
      if (k == tk) {
        g = ls + Tfb_g[lane];
      } else if (mask[b * S_ + tk] == 1) {
        const int u = tk - 1 - k;
        const float mlin = Mg_lin[((size_t)b * S_ + u) * 64 + lane];
        const float M = (mlin > 0.f) ? (__logf(mlin) + cs_g[b * S_ + u]) : -1e30f;
        g = ls + M;
      } else {
        g = NEGV;
      }
    }
    const float v = g + t2e;
    vals[k] = v;
    mx = fmaxf(mx, v);
  }
#pragma unroll
  for (int off = 32; off > 0; off >>= 1) mx = fmaxf(mx, __shfl_xor(mx, off));
  float s = 0.f;
#pragma unroll
  for (int k = 0; k < 8; k++) s += __expf(vals[k] - mx);
#pragma unroll
  for (int off = 32; off > 0; off >>= 1) s += __shfl_xor(s, off);
  if (lane == 0) out[b] = __logf(s) + mx;
}

// ---------------------------------------------------------------------------
extern "C" void kernel_launch(void* const* d_in, const int* in_sizes, int n_in,
                              void* d_out, int out_size, void* d_ws, size_t ws_size,
                              hipStream_t stream) {
  const float* wr     = (const float*)d_in[0];
  const int*   mask   = (const int*)d_in[1];
  const float* conv_w = (const float*)d_in[2];
  const float* conv_b = (const float*)d_in[3];
  const float* cls_w  = (const float*)d_in[4];
  const float* cls_b  = (const float*)d_in[5];
  const float* T      = (const float*)d_in[6];
  const float* Tfb    = (const float*)d_in[7];
  const float* T2e    = (const float*)d_in[8];
  float* out = (float*)d_out;

  float* ws = (float*)d_ws;
  bf16_t* Vt    = (bf16_t*)ws;                      // [512][4096] bf16 (4 MB)
  bf16_t* Awr   = (bf16_t*)(ws + 1048576);          // [8192][512] bf16 (8 MB)
  float*  bias2 = ws + 3145728;                     // [8][64]
  unsigned int* ELSd = (unsigned int*)(ws + 3146240);  // [4][8192][64] dwords (8 MB)
  float*  Mg    = ws + 5243392;                     // [32][256][64] (2 MB)
  float*  cs    = ws + 5767680;                     // [32][256]
  bf16_t* clsb  = (bf16_t*)(ws + 5775872);          // [64][512] bf16

  cast_kernel<<<2064, 256, 0, stream>>>(wr, Awr, cls_w, clsb);
  w2_kernel<<<dim3(32, 8), 256, 0, stream>>>(conv_w, clsb, Vt, conv_b, cls_w, cls_b, bias2);
  ls_mfma<<<dim3(128, 2), 256, 0, stream>>>(Awr, Vt, bias2, mask, ELSd);
  dp_kernel<<<32, 64, 0, stream>>>(T, Tfb, ELSd, Mg, cs);
  final_kernel<<<32, 64, 0, stream>>>(mask, Tfb, T2e, ELSd, Mg, cs, out);
}